// Round 10
// baseline (164.464 us; speedup 1.0000x reference)
//
#include <hip/hip_runtime.h>

#define NTEST  16384
#define NTRAIN 8192
#define DIM    64
#define NCOLSPLIT 16
#define TPW    (NTRAIN / 32 / NCOLSPLIT)   // 16 col-tiles per wave

typedef _Float16 f16x8  __attribute__((ext_vector_type(8)));
typedef float    f32x16 __attribute__((ext_vector_type(16)));

#define LOG2E 1.4426950408889634f

// One wave per row. Rows [0,NTEST) = test_X -> A_hi (row-major) + nx2=cn*nx.
// Rows [NTEST,..) = train_X -> B_hi in TILE-MAJOR fragment layout +
// wt = alpha * exp2(cn*nt)  (train-norm folded into the weight).
// hi-only f16 (calibrated: ~4x margin vs threshold, round-9 measured 1.46e-11).
// Tile-major: for train row r, dim k:
//   flat = (r>>5)*2048 + (k>>4)*512 + (((k>>3)&1)*32 + (r&31))*8 + (k&7)
__global__ __launch_bounds__(256) void krr_prep(
    const float* __restrict__ test_X, const float* __restrict__ train_X,
    const float* __restrict__ alphas, const float* __restrict__ lengthscale,
    _Float16* __restrict__ A_hi, _Float16* __restrict__ B_hi,
    float* __restrict__ nx2, float* __restrict__ wt)
{
    int gwave = (blockIdx.x * 256 + threadIdx.x) >> 6;
    int lane  = threadIdx.x & 63;           // = dim index k
    bool is_test = gwave < NTEST;
    int row = is_test ? gwave : gwave - NTEST;
    const float* src = is_test ? test_X : train_X;

    float x = src[(size_t)row * DIM + lane];
    _Float16 h = (_Float16)x;                // RNE to f16

    if (is_test) {
        A_hi[(size_t)row * DIM + lane] = h;
    } else {
        int t  = row >> 5, lr = row & 31;
        int kk = lane >> 4, hi = (lane >> 3) & 1, e = lane & 7;
        size_t dst = (size_t)t * 2048 + (size_t)kk * 512 + (size_t)(hi * 32 + lr) * 8 + e;
        B_hi[dst] = h;
    }

    float s = x * x;
    s += __shfl_xor(s, 1);  s += __shfl_xor(s, 2);  s += __shfl_xor(s, 4);
    s += __shfl_xor(s, 8);  s += __shfl_xor(s, 16); s += __shfl_xor(s, 32);
    if (lane == 0) {
        float ls   = lengthscale[0];
        float inv2 = 1.0f / (ls * ls);
        float cn   = -0.5f * inv2 * LOG2E;   // log2-domain norm coefficient
        if (is_test) nx2[row] = s * cn;
        else         wt[row]  = alphas[row] * __builtin_amdgcn_exp2f(cn * s);
    }
}

// ONE WAVE PER BLOCK (krr_mfma has no inter-wave communication — 64-thread
// blocks let the dispatcher fill CUs to the HW wave cap instead of the
// observed 4-WG/CU plateau with 256-thread blocks). Each wave: 32 test rows
// x (NTRAIN/NCOLSPLIT) train cols = TPW=16 tiles, 2x the round-9 tiles/wave
// (halves setup/drain amortization) at the SAME total wave count.
// 4 MFMA per tile (hi*hi only, chained). Epilogue/row: fma + exp2 + fma.
// K*alpha = exp2(s1*C + nx2[row]) * wt[col].
__global__ __launch_bounds__(64, 8) void krr_mfma(
    const _Float16* __restrict__ A_hi, const _Float16* __restrict__ B_hi,
    const float* __restrict__ nx2, const float* __restrict__ wt,
    const float* __restrict__ lengthscale, float* __restrict__ out)
{
    const int lane  = threadIdx.x & 63;
    const int rbase = blockIdx.x * 32;
    const int t0    = blockIdx.y * TPW;

    const float ls   = lengthscale[0];
    const float inv2 = 1.0f / (ls * ls);
    const float s1   = inv2 * LOG2E;         // dot coefficient (log2 domain)

    const int arow = rbase + (lane & 31);
    const int koff = (lane >> 5) * 8;        // canonical k-map, same for A and B

    // A fragments, loop-invariant: 4 x 16B = 16 VGPRs
    f16x8 ah[4];
    #pragma unroll
    for (int kk = 0; kk < 4; ++kk)
        ah[kk] = *reinterpret_cast<const f16x8*>(A_hi + (size_t)arow * DIM + kk * 16 + koff);

    // per-lane row constants: cn*nx for the 16 C/D rows this lane holds
    float nxc[16];
    #pragma unroll
    for (int r = 0; r < 16; ++r) {
        int row = (r & 3) + 8 * (r >> 2) + 4 * (lane >> 5);
        nxc[r] = nx2[rbase + row];
    }

    float acc[16];
    #pragma unroll
    for (int r = 0; r < 16; ++r) acc[r] = 0.0f;

    for (int t = t0; t < t0 + TPW; ++t) {
        // Fragment loads: fully contiguous 1KB per instruction.
        const _Float16* ph = B_hi + (size_t)t * 2048 + (size_t)lane * 8;
        f16x8 bh[4];
        #pragma unroll
        for (int kk = 0; kk < 4; ++kk)
            bh[kk] = *reinterpret_cast<const f16x8*>(ph + kk * 512);
        const float w = wt[t * 32 + (lane & 31)];

        f32x16 C = {};
        #pragma unroll
        for (int kk = 0; kk < 4; ++kk)
            C = __builtin_amdgcn_mfma_f32_32x32x16_f16(ah[kk], bh[kk], C, 0, 0, 0);

        #pragma unroll
        for (int r = 0; r < 16; ++r) {
            float arg = fmaf(C[r], s1, nxc[r]);          // log2 domain
            acc[r] = fmaf(__builtin_amdgcn_exp2f(arg), w, acc[r]);
        }
    }

    // Sum over the 32 train cols held across lanes of the same half.
    #pragma unroll
    for (int r = 0; r < 16; ++r) {
        float v = acc[r];
        v += __shfl_xor(v, 1);  v += __shfl_xor(v, 2);  v += __shfl_xor(v, 4);
        v += __shfl_xor(v, 8);  v += __shfl_xor(v, 16);
        if ((lane & 31) == 0) {
            int row = (r & 3) + 8 * (r >> 2) + 4 * (lane >> 5);
            atomicAdd(&out[rbase + row], v);
        }
    }
}

// ---------------- fallback (round-1 kernel, known-good) ----------------
#define TCHUNK 512
#define NCHUNK (NTRAIN / TCHUNK)
__global__ __launch_bounds__(256, 4) void krr_main(
    const float* __restrict__ test_X, const float* __restrict__ train_X,
    const float* __restrict__ alphas, const float* __restrict__ lengthscale,
    float* __restrict__ out)
{
    __shared__ float nt_lds[TCHUNK];
    __shared__ float al_lds[TCHUNK];
    const int tid = threadIdx.x;
    const int i   = blockIdx.x * 256 + tid;
    const int j0  = blockIdx.y * TCHUNK;
    const float ls   = lengthscale[0];
    const float inv2 = 1.0f / (ls * ls);
    for (int jj = tid; jj < TCHUNK; jj += 256) {
        const float4* tr = reinterpret_cast<const float4*>(train_X + (size_t)(j0 + jj) * DIM);
        float s = 0.f;
        #pragma unroll
        for (int k = 0; k < DIM / 4; ++k) {
            float4 t = tr[k];
            s += t.x * t.x + t.y * t.y + t.z * t.z + t.w * t.w;
        }
        nt_lds[jj] = s * inv2;
        al_lds[jj] = alphas[j0 + jj];
    }
    __syncthreads();
    float xr[DIM]; float nxv = 0.f;
    {
        const float4* xp = reinterpret_cast<const float4*>(test_X + (size_t)i * DIM);
        #pragma unroll
        for (int k = 0; k < DIM / 4; ++k) {
            float4 v = xp[k];
            xr[4*k+0] = v.x; xr[4*k+1] = v.y; xr[4*k+2] = v.z; xr[4*k+3] = v.w;
            nxv += v.x*v.x + v.y*v.y + v.z*v.z + v.w*v.w;
        }
        nxv *= inv2;
        #pragma unroll
        for (int k = 0; k < DIM; ++k) xr[k] *= inv2;
    }
    float acc = 0.f;
    for (int jj = 0; jj < TCHUNK; ++jj) {
        const float* trow = train_X + (size_t)(j0 + jj) * DIM;
        float d0 = 0.f, d1 = 0.f, d2 = 0.f, d3 = 0.f;
        #pragma unroll
        for (int k4 = 0; k4 < DIM / 4; ++k4) {
            float4 t = reinterpret_cast<const float4*>(trow)[k4];
            d0 = fmaf(xr[4*k4+0], t.x, d0);
            d1 = fmaf(xr[4*k4+1], t.y, d1);
            d2 = fmaf(xr[4*k4+2], t.z, d2);
            d3 = fmaf(xr[4*k4+3], t.w, d3);
        }
        float dot = (d0 + d1) + (d2 + d3);
        float sq  = nxv + nt_lds[jj] - 2.0f * dot;
        sq = fmaxf(sq, 0.0f);
        acc = fmaf(__expf(-0.5f * sq), al_lds[jj], acc);
    }
    atomicAdd(&out[i], acc);
}

extern "C" void kernel_launch(void* const* d_in, const int* in_sizes, int n_in,
                              void* d_out, int out_size, void* d_ws, size_t ws_size,
                              hipStream_t stream) {
    const float* test_X      = (const float*)d_in[0];
    const float* train_X     = (const float*)d_in[1];
    const float* alphas      = (const float*)d_in[2];
    const float* lengthscale = (const float*)d_in[3];
    float* out = (float*)d_out;

    hipMemsetAsync(out, 0, NTEST * sizeof(float), stream);

    const size_t need = (size_t)(NTEST + NTRAIN) * DIM * sizeof(_Float16)
                      + (NTEST + NTRAIN) * sizeof(float);
    if (ws_size >= need) {
        _Float16* A_hi = (_Float16*)d_ws;
        _Float16* B_hi = A_hi + (size_t)NTEST * DIM;
        float*    nx2  = (float*)(B_hi + (size_t)NTRAIN * DIM);
        float*    wtp  = nx2 + NTEST;

        krr_prep<<<(NTEST + NTRAIN) / 4, 256, 0, stream>>>(
            test_X, train_X, alphas, lengthscale, A_hi, B_hi, nx2, wtp);

        dim3 grid(NTEST / 32, NCOLSPLIT);
        krr_mfma<<<grid, 64, 0, stream>>>(A_hi, B_hi, nx2, wtp,
                                          lengthscale, out);
    } else {
        dim3 grid(NTEST / 256, NCHUNK);
        krr_main<<<grid, 256, 0, stream>>>(test_X, train_X, alphas, lengthscale, out);
    }
}

// Round 11
// 57.622 us; speedup vs baseline: 2.8542x; 2.8542x over previous
//
#include <hip/hip_runtime.h>

#define NTEST  16384
#define NTRAIN 8192
#define DIM    64
#define NCOLSPLIT 16
#define TPW    (NTRAIN / 32 / NCOLSPLIT)   // 16 col-tiles per wave

typedef _Float16 f16x8  __attribute__((ext_vector_type(8)));
typedef float    f32x16 __attribute__((ext_vector_type(16)));

#define LOG2E 1.4426950408889634f

// One wave per row. Rows [0,NTEST) = test_X -> A_hi (row-major) + nx2=cn*nx.
// Rows [NTEST,..) = train_X -> B_hi in TILE-MAJOR fragment layout +
// wt = alpha * exp2(cn*nt)  (train-norm folded into the weight).
// hi-only f16 (calibrated: 4x margin, round-9 measured absmax 1.46e-11).
// Tile-major: for train row r, dim k:
//   flat = (r>>5)*2048 + (k>>4)*512 + (((k>>3)&1)*32 + (r&31))*8 + (k&7)
__global__ __launch_bounds__(256) void krr_prep(
    const float* __restrict__ test_X, const float* __restrict__ train_X,
    const float* __restrict__ alphas, const float* __restrict__ lengthscale,
    _Float16* __restrict__ A_hi, _Float16* __restrict__ B_hi,
    float* __restrict__ nx2, float* __restrict__ wt)
{
    int gwave = (blockIdx.x * 256 + threadIdx.x) >> 6;
    int lane  = threadIdx.x & 63;           // = dim index k
    bool is_test = gwave < NTEST;
    int row = is_test ? gwave : gwave - NTEST;
    const float* src = is_test ? test_X : train_X;

    float x = src[(size_t)row * DIM + lane];
    _Float16 h = (_Float16)x;                // RNE to f16

    if (is_test) {
        A_hi[(size_t)row * DIM + lane] = h;
    } else {
        int t  = row >> 5, lr = row & 31;
        int kk = lane >> 4, hi = (lane >> 3) & 1, e = lane & 7;
        size_t dst = (size_t)t * 2048 + (size_t)kk * 512 + (size_t)(hi * 32 + lr) * 8 + e;
        B_hi[dst] = h;
    }

    float s = x * x;
    s += __shfl_xor(s, 1);  s += __shfl_xor(s, 2);  s += __shfl_xor(s, 4);
    s += __shfl_xor(s, 8);  s += __shfl_xor(s, 16); s += __shfl_xor(s, 32);
    if (lane == 0) {
        float ls   = lengthscale[0];
        float inv2 = 1.0f / (ls * ls);
        float cn   = -0.5f * inv2 * LOG2E;   // log2-domain norm coefficient
        if (is_test) nx2[row] = s * cn;
        else         wt[row]  = alphas[row] * __builtin_amdgcn_exp2f(cn * s);
    }
}

// ONE WAVE PER BLOCK. Round-10 lesson: __launch_bounds__(64,8) capped the
// allocator at 512/8=64 VGPR while the body needs ~80 -> scratch spill,
// 270 MB HBM fetch, 2.5x regression. NO waves-per-EU minimum here: the
// compiler keeps its natural ~40 VGPR (round-9 measured), and residency
// is limited only by the 8-wave/SIMD HW slots.
// Each wave: 32 test rows x 512 train cols = TPW=16 tiles.
// 4 MFMA per tile (hi*hi only, chained). Epilogue/row: fma + exp2 + fma.
// K*alpha = exp2(s1*C + nx2[row]) * wt[col].
__global__ __launch_bounds__(64) void krr_mfma(
    const _Float16* __restrict__ A_hi, const _Float16* __restrict__ B_hi,
    const float* __restrict__ nx2, const float* __restrict__ wt,
    const float* __restrict__ lengthscale, float* __restrict__ out)
{
    const int lane  = threadIdx.x & 63;
    const int rbase = blockIdx.x * 32;
    const int t0    = blockIdx.y * TPW;

    const float ls   = lengthscale[0];
    const float inv2 = 1.0f / (ls * ls);
    const float s1   = inv2 * LOG2E;         // dot coefficient (log2 domain)

    const int arow = rbase + (lane & 31);
    const int koff = (lane >> 5) * 8;        // canonical k-map, same for A and B

    // A fragments, loop-invariant: 4 x 16B = 16 VGPRs
    f16x8 ah[4];
    #pragma unroll
    for (int kk = 0; kk < 4; ++kk)
        ah[kk] = *reinterpret_cast<const f16x8*>(A_hi + (size_t)arow * DIM + kk * 16 + koff);

    // per-lane row constants: cn*nx for the 16 C/D rows this lane holds
    float nxc[16];
    #pragma unroll
    for (int r = 0; r < 16; ++r) {
        int row = (r & 3) + 8 * (r >> 2) + 4 * (lane >> 5);
        nxc[r] = nx2[rbase + row];
    }

    float acc[16];
    #pragma unroll
    for (int r = 0; r < 16; ++r) acc[r] = 0.0f;

    for (int t = t0; t < t0 + TPW; ++t) {
        // Fragment loads: fully contiguous 1KB per instruction.
        const _Float16* ph = B_hi + (size_t)t * 2048 + (size_t)lane * 8;
        f16x8 bh[4];
        #pragma unroll
        for (int kk = 0; kk < 4; ++kk)
            bh[kk] = *reinterpret_cast<const f16x8*>(ph + kk * 512);
        const float w = wt[t * 32 + (lane & 31)];

        f32x16 C = {};
        #pragma unroll
        for (int kk = 0; kk < 4; ++kk)
            C = __builtin_amdgcn_mfma_f32_32x32x16_f16(ah[kk], bh[kk], C, 0, 0, 0);

        #pragma unroll
        for (int r = 0; r < 16; ++r) {
            float arg = fmaf(C[r], s1, nxc[r]);          // log2 domain
            acc[r] = fmaf(__builtin_amdgcn_exp2f(arg), w, acc[r]);
        }
    }

    // Sum over the 32 train cols held across lanes of the same half.
    #pragma unroll
    for (int r = 0; r < 16; ++r) {
        float v = acc[r];
        v += __shfl_xor(v, 1);  v += __shfl_xor(v, 2);  v += __shfl_xor(v, 4);
        v += __shfl_xor(v, 8);  v += __shfl_xor(v, 16);
        if ((lane & 31) == 0) {
            int row = (r & 3) + 8 * (r >> 2) + 4 * (lane >> 5);
            atomicAdd(&out[rbase + row], v);
        }
    }
}

// ---------------- fallback (round-1 kernel, known-good) ----------------
#define TCHUNK 512
#define NCHUNK (NTRAIN / TCHUNK)
__global__ __launch_bounds__(256, 4) void krr_main(
    const float* __restrict__ test_X, const float* __restrict__ train_X,
    const float* __restrict__ alphas, const float* __restrict__ lengthscale,
    float* __restrict__ out)
{
    __shared__ float nt_lds[TCHUNK];
    __shared__ float al_lds[TCHUNK];
    const int tid = threadIdx.x;
    const int i   = blockIdx.x * 256 + tid;
    const int j0  = blockIdx.y * TCHUNK;
    const float ls   = lengthscale[0];
    const float inv2 = 1.0f / (ls * ls);
    for (int jj = tid; jj < TCHUNK; jj += 256) {
        const float4* tr = reinterpret_cast<const float4*>(train_X + (size_t)(j0 + jj) * DIM);
        float s = 0.f;
        #pragma unroll
        for (int k = 0; k < DIM / 4; ++k) {
            float4 t = tr[k];
            s += t.x * t.x + t.y * t.y + t.z * t.z + t.w * t.w;
        }
        nt_lds[jj] = s * inv2;
        al_lds[jj] = alphas[j0 + jj];
    }
    __syncthreads();
    float xr[DIM]; float nxv = 0.f;
    {
        const float4* xp = reinterpret_cast<const float4*>(test_X + (size_t)i * DIM);
        #pragma unroll
        for (int k = 0; k < DIM / 4; ++k) {
            float4 v = xp[k];
            xr[4*k+0] = v.x; xr[4*k+1] = v.y; xr[4*k+2] = v.z; xr[4*k+3] = v.w;
            nxv += v.x*v.x + v.y*v.y + v.z*v.z + v.w*v.w;
        }
        nxv *= inv2;
        #pragma unroll
        for (int k = 0; k < DIM; ++k) xr[k] *= inv2;
    }
    float acc = 0.f;
    for (int jj = 0; jj < TCHUNK; ++jj) {
        const float* trow = train_X + (size_t)(j0 + jj) * DIM;
        float d0 = 0.f, d1 = 0.f, d2 = 0.f, d3 = 0.f;
        #pragma unroll
        for (int k4 = 0; k4 < DIM / 4; ++k4) {
            float4 t = reinterpret_cast<const float4*>(trow)[k4];
            d0 = fmaf(xr[4*k4+0], t.x, d0);
            d1 = fmaf(xr[4*k4+1], t.y, d1);
            d2 = fmaf(xr[4*k4+2], t.z, d2);
            d3 = fmaf(xr[4*k4+3], t.w, d3);
        }
        float dot = (d0 + d1) + (d2 + d3);
        float sq  = nxv + nt_lds[jj] - 2.0f * dot;
        sq = fmaxf(sq, 0.0f);
        acc = fmaf(__expf(-0.5f * sq), al_lds[jj], acc);
    }
    atomicAdd(&out[i], acc);
}

extern "C" void kernel_launch(void* const* d_in, const int* in_sizes, int n_in,
                              void* d_out, int out_size, void* d_ws, size_t ws_size,
                              hipStream_t stream) {
    const float* test_X      = (const float*)d_in[0];
    const float* train_X     = (const float*)d_in[1];
    const float* alphas      = (const float*)d_in[2];
    const float* lengthscale = (const float*)d_in[3];
    float* out = (float*)d_out;

    hipMemsetAsync(out, 0, NTEST * sizeof(float), stream);

    const size_t need = (size_t)(NTEST + NTRAIN) * DIM * sizeof(_Float16)
                      + (NTEST + NTRAIN) * sizeof(float);
    if (ws_size >= need) {
        _Float16* A_hi = (_Float16*)d_ws;
        _Float16* B_hi = A_hi + (size_t)NTEST * DIM;
        float*    nx2  = (float*)(B_hi + (size_t)NTRAIN * DIM);
        float*    wtp  = nx2 + NTEST;

        krr_prep<<<(NTEST + NTRAIN) / 4, 256, 0, stream>>>(
            test_X, train_X, alphas, lengthscale, A_hi, B_hi, nx2, wtp);

        dim3 grid(NTEST / 32, NCOLSPLIT);
        krr_mfma<<<grid, 64, 0, stream>>>(A_hi, B_hi, nx2, wtp,
                                          lengthscale, out);
    } else {
        dim3 grid(NTEST / 256, NCHUNK);
        krr_main<<<grid, 256, 0, stream>>>(test_X, train_X, alphas, lengthscale, out);
    }
}

// Round 12
// 57.342 us; speedup vs baseline: 2.8681x; 1.0049x over previous
//
#include <hip/hip_runtime.h>

#define NTEST  16384
#define NTRAIN 8192
#define DIM    64
#define NCOLSPLIT 16
#define TPW    (NTRAIN / 32 / NCOLSPLIT)   // 16 col-tiles per wave
#define WPB    8                            // waves per block (512 threads)

typedef _Float16 f16x8  __attribute__((ext_vector_type(8)));
typedef float    f32x16 __attribute__((ext_vector_type(16)));

#define LOG2E 1.4426950408889634f

// One wave per row. Rows [0,NTEST) = test_X -> A_hi (row-major) + nx2=cn*nx.
// Rows [NTEST,..) = train_X -> B_hi in TILE-MAJOR fragment layout +
// wt = alpha * exp2(cn*nt)  (train-norm folded into the weight).
// hi-only f16 (calibrated: 4x margin, round-9/11 measured absmax 1.46e-11).
// Tile-major: for train row r, dim k:
//   flat = (r>>5)*2048 + (k>>4)*512 + (((k>>3)&1)*32 + (r&31))*8 + (k&7)
__global__ __launch_bounds__(256) void krr_prep(
    const float* __restrict__ test_X, const float* __restrict__ train_X,
    const float* __restrict__ alphas, const float* __restrict__ lengthscale,
    _Float16* __restrict__ A_hi, _Float16* __restrict__ B_hi,
    float* __restrict__ nx2, float* __restrict__ wt)
{
    int gwave = (blockIdx.x * 256 + threadIdx.x) >> 6;
    int lane  = threadIdx.x & 63;           // = dim index k
    bool is_test = gwave < NTEST;
    int row = is_test ? gwave : gwave - NTEST;
    const float* src = is_test ? test_X : train_X;

    float x = src[(size_t)row * DIM + lane];
    _Float16 h = (_Float16)x;                // RNE to f16

    if (is_test) {
        A_hi[(size_t)row * DIM + lane] = h;
    } else {
        int t  = row >> 5, lr = row & 31;
        int kk = lane >> 4, hi = (lane >> 3) & 1, e = lane & 7;
        size_t dst = (size_t)t * 2048 + (size_t)kk * 512 + (size_t)(hi * 32 + lr) * 8 + e;
        B_hi[dst] = h;
    }

    float s = x * x;
    s += __shfl_xor(s, 1);  s += __shfl_xor(s, 2);  s += __shfl_xor(s, 4);
    s += __shfl_xor(s, 8);  s += __shfl_xor(s, 16); s += __shfl_xor(s, 32);
    if (lane == 0) {
        float ls   = lengthscale[0];
        float inv2 = 1.0f / (ls * ls);
        float cn   = -0.5f * inv2 * LOG2E;   // log2-domain norm coefficient
        if (is_test) nx2[row] = s * cn;
        else         wt[row]  = alphas[row] * __builtin_amdgcn_exp2f(cn * s);
    }
}

// 512-THREAD WG = 8 INDEPENDENT WAVES (no barriers, no LDS). Residency
// lessons: 64-thread WGs hit a ~8 WG/CU dispatch cap (round 11: 25% occ);
// 1-wave-per-EU register caps spill (round 10). Packing 8 waves/WG gives
// 32 waves/CU from 4 WG slots; VGPR 68 allows ~7 waves/SIMD.
// Wave w handles col-split blockIdx.y*8+w: 32 test rows x 512 train cols
// = TPW=16 tiles. Per-wave body identical to round 11 (pure residency A/B).
// 4 MFMA per tile (hi*hi, chained). Epilogue/row: fma + exp2 + fma.
// K*alpha = exp2(s1*C + nx2[row]) * wt[col].
__global__ __launch_bounds__(512) void krr_mfma(
    const _Float16* __restrict__ A_hi, const _Float16* __restrict__ B_hi,
    const float* __restrict__ nx2, const float* __restrict__ wt,
    const float* __restrict__ lengthscale, float* __restrict__ out)
{
    const int lane  = threadIdx.x & 63;
    const int wave  = threadIdx.x >> 6;
    const int rbase = blockIdx.x * 32;
    const int t0    = (blockIdx.y * WPB + wave) * TPW;

    const float ls   = lengthscale[0];
    const float inv2 = 1.0f / (ls * ls);
    const float s1   = inv2 * LOG2E;         // dot coefficient (log2 domain)

    const int arow = rbase + (lane & 31);
    const int koff = (lane >> 5) * 8;        // canonical k-map, same for A and B

    // A fragments, loop-invariant: 4 x 16B = 16 VGPRs
    f16x8 ah[4];
    #pragma unroll
    for (int kk = 0; kk < 4; ++kk)
        ah[kk] = *reinterpret_cast<const f16x8*>(A_hi + (size_t)arow * DIM + kk * 16 + koff);

    // per-lane row constants: cn*nx for the 16 C/D rows this lane holds
    float nxc[16];
    #pragma unroll
    for (int r = 0; r < 16; ++r) {
        int row = (r & 3) + 8 * (r >> 2) + 4 * (lane >> 5);
        nxc[r] = nx2[rbase + row];
    }

    float acc[16];
    #pragma unroll
    for (int r = 0; r < 16; ++r) acc[r] = 0.0f;

    for (int t = t0; t < t0 + TPW; ++t) {
        // Fragment loads: fully contiguous 1KB per instruction.
        const _Float16* ph = B_hi + (size_t)t * 2048 + (size_t)lane * 8;
        f16x8 bh[4];
        #pragma unroll
        for (int kk = 0; kk < 4; ++kk)
            bh[kk] = *reinterpret_cast<const f16x8*>(ph + kk * 512);
        const float w = wt[t * 32 + (lane & 31)];

        f32x16 C = {};
        #pragma unroll
        for (int kk = 0; kk < 4; ++kk)
            C = __builtin_amdgcn_mfma_f32_32x32x16_f16(ah[kk], bh[kk], C, 0, 0, 0);

        #pragma unroll
        for (int r = 0; r < 16; ++r) {
            float arg = fmaf(C[r], s1, nxc[r]);          // log2 domain
            acc[r] = fmaf(__builtin_amdgcn_exp2f(arg), w, acc[r]);
        }
    }

    // Sum over the 32 train cols held across lanes of the same half.
    #pragma unroll
    for (int r = 0; r < 16; ++r) {
        float v = acc[r];
        v += __shfl_xor(v, 1);  v += __shfl_xor(v, 2);  v += __shfl_xor(v, 4);
        v += __shfl_xor(v, 8);  v += __shfl_xor(v, 16);
        if ((lane & 31) == 0) {
            int row = (r & 3) + 8 * (r >> 2) + 4 * (lane >> 5);
            atomicAdd(&out[rbase + row], v);
        }
    }
}

// ---------------- fallback (round-1 kernel, known-good) ----------------
#define TCHUNK 512
#define NCHUNK (NTRAIN / TCHUNK)
__global__ __launch_bounds__(256, 4) void krr_main(
    const float* __restrict__ test_X, const float* __restrict__ train_X,
    const float* __restrict__ alphas, const float* __restrict__ lengthscale,
    float* __restrict__ out)
{
    __shared__ float nt_lds[TCHUNK];
    __shared__ float al_lds[TCHUNK];
    const int tid = threadIdx.x;
    const int i   = blockIdx.x * 256 + tid;
    const int j0  = blockIdx.y * TCHUNK;
    const float ls   = lengthscale[0];
    const float inv2 = 1.0f / (ls * ls);
    for (int jj = tid; jj < TCHUNK; jj += 256) {
        const float4* tr = reinterpret_cast<const float4*>(train_X + (size_t)(j0 + jj) * DIM);
        float s = 0.f;
        #pragma unroll
        for (int k = 0; k < DIM / 4; ++k) {
            float4 t = tr[k];
            s += t.x * t.x + t.y * t.y + t.z * t.z + t.w * t.w;
        }
        nt_lds[jj] = s * inv2;
        al_lds[jj] = alphas[j0 + jj];
    }
    __syncthreads();
    float xr[DIM]; float nxv = 0.f;
    {
        const float4* xp = reinterpret_cast<const float4*>(test_X + (size_t)i * DIM);
        #pragma unroll
        for (int k = 0; k < DIM / 4; ++k) {
            float4 v = xp[k];
            xr[4*k+0] = v.x; xr[4*k+1] = v.y; xr[4*k+2] = v.z; xr[4*k+3] = v.w;
            nxv += v.x*v.x + v.y*v.y + v.z*v.z + v.w*v.w;
        }
        nxv *= inv2;
        #pragma unroll
        for (int k = 0; k < DIM; ++k) xr[k] *= inv2;
    }
    float acc = 0.f;
    for (int jj = 0; jj < TCHUNK; ++jj) {
        const float* trow = train_X + (size_t)(j0 + jj) * DIM;
        float d0 = 0.f, d1 = 0.f, d2 = 0.f, d3 = 0.f;
        #pragma unroll
        for (int k4 = 0; k4 < DIM / 4; ++k4) {
            float4 t = reinterpret_cast<const float4*>(trow)[k4];
            d0 = fmaf(xr[4*k4+0], t.x, d0);
            d1 = fmaf(xr[4*k4+1], t.y, d1);
            d2 = fmaf(xr[4*k4+2], t.z, d2);
            d3 = fmaf(xr[4*k4+3], t.w, d3);
        }
        float dot = (d0 + d1) + (d2 + d3);
        float sq  = nxv + nt_lds[jj] - 2.0f * dot;
        sq = fmaxf(sq, 0.0f);
        acc = fmaf(__expf(-0.5f * sq), al_lds[jj], acc);
    }
    atomicAdd(&out[i], acc);
}

extern "C" void kernel_launch(void* const* d_in, const int* in_sizes, int n_in,
                              void* d_out, int out_size, void* d_ws, size_t ws_size,
                              hipStream_t stream) {
    const float* test_X      = (const float*)d_in[0];
    const float* train_X     = (const float*)d_in[1];
    const float* alphas      = (const float*)d_in[2];
    const float* lengthscale = (const float*)d_in[3];
    float* out = (float*)d_out;

    hipMemsetAsync(out, 0, NTEST * sizeof(float), stream);

    const size_t need = (size_t)(NTEST + NTRAIN) * DIM * sizeof(_Float16)
                      + (NTEST + NTRAIN) * sizeof(float);
    if (ws_size >= need) {
        _Float16* A_hi = (_Float16*)d_ws;
        _Float16* B_hi = A_hi + (size_t)NTEST * DIM;
        float*    nx2  = (float*)(B_hi + (size_t)NTRAIN * DIM);
        float*    wtp  = nx2 + NTEST;

        krr_prep<<<(NTEST + NTRAIN) / 4, 256, 0, stream>>>(
            test_X, train_X, alphas, lengthscale, A_hi, B_hi, nx2, wtp);

        dim3 grid(NTEST / 32, NCOLSPLIT / WPB);
        krr_mfma<<<grid, 64 * WPB, 0, stream>>>(A_hi, B_hi, nx2, wtp,
                                                lengthscale, out);
    } else {
        dim3 grid(NTEST / 256, NCHUNK);
        krr_main<<<grid, 256, 0, stream>>>(test_X, train_X, alphas, lengthscale, out);
    }
}

// Round 13
// 53.703 us; speedup vs baseline: 3.0625x; 1.0678x over previous
//
#include <hip/hip_runtime.h>

#define NTEST  16384
#define NTRAIN 8192
#define DIM    64
#define NCOLSPLIT 16
#define TPW    (NTRAIN / 32 / NCOLSPLIT)   // 16 col-tiles per wave
#define WPB    8                            // waves per block (512 threads)

typedef _Float16 f16x8  __attribute__((ext_vector_type(8)));
typedef float    f32x16 __attribute__((ext_vector_type(16)));

#define LOG2E 1.4426950408889634f

// One wave per row. Rows [0,NTEST) = test_X -> A_hi (row-major) + nx2=cn*nx.
// Rows [NTEST,..) = train_X -> B_hi in TILE-MAJOR fragment layout +
// wt = alpha * exp2(cn*nt)  (train-norm folded into the weight).
// hi-only f16 (calibrated: 4x margin, rounds 9/11/12 measured 1.455e-11).
// Tile-major: for train row r, dim k:
//   flat = (r>>5)*2048 + (k>>4)*512 + (((k>>3)&1)*32 + (r&31))*8 + (k&7)
__global__ __launch_bounds__(256) void krr_prep(
    const float* __restrict__ test_X, const float* __restrict__ train_X,
    const float* __restrict__ alphas, const float* __restrict__ lengthscale,
    _Float16* __restrict__ A_hi, _Float16* __restrict__ B_hi,
    float* __restrict__ nx2, float* __restrict__ wt)
{
    int gwave = (blockIdx.x * 256 + threadIdx.x) >> 6;
    int lane  = threadIdx.x & 63;           // = dim index k
    bool is_test = gwave < NTEST;
    int row = is_test ? gwave : gwave - NTEST;
    const float* src = is_test ? test_X : train_X;

    float x = src[(size_t)row * DIM + lane];
    _Float16 h = (_Float16)x;                // RNE to f16

    if (is_test) {
        A_hi[(size_t)row * DIM + lane] = h;
    } else {
        int t  = row >> 5, lr = row & 31;
        int kk = lane >> 4, hi = (lane >> 3) & 1, e = lane & 7;
        size_t dst = (size_t)t * 2048 + (size_t)kk * 512 + (size_t)(hi * 32 + lr) * 8 + e;
        B_hi[dst] = h;
    }

    float s = x * x;
    s += __shfl_xor(s, 1);  s += __shfl_xor(s, 2);  s += __shfl_xor(s, 4);
    s += __shfl_xor(s, 8);  s += __shfl_xor(s, 16); s += __shfl_xor(s, 32);
    if (lane == 0) {
        float ls   = lengthscale[0];
        float inv2 = 1.0f / (ls * ls);
        float cn   = -0.5f * inv2 * LOG2E;   // log2-domain norm coefficient
        if (is_test) nx2[row] = s * cn;
        else         wt[row]  = alphas[row] * __builtin_amdgcn_exp2f(cn * s);
    }
}

// 512-thread WG = 8 independent waves. LATENCY-BOUND diagnosis (rounds
// 9-12: occupancy 25-50% with dur pinned ~48-55 us, no pipe >35%): the fix
// is intra-wave ILP, not residency. TWO-TILE UNROLL: independent register
// sets (bhA/bhB, CA/CB, wA/wB — all compile-time indexed, rule #20) give
// two independent load streams + two independent 4-deep MFMA chains + two
// epilogues in flight per wave. Math identical to rounds 9-12.
// K*alpha = exp2(s1*C + nx2[row]) * wt[col].
__global__ __launch_bounds__(512) void krr_mfma(
    const _Float16* __restrict__ A_hi, const _Float16* __restrict__ B_hi,
    const float* __restrict__ nx2, const float* __restrict__ wt,
    const float* __restrict__ lengthscale, float* __restrict__ out)
{
    const int lane  = threadIdx.x & 63;
    const int wave  = threadIdx.x >> 6;
    const int rbase = blockIdx.x * 32;
    const int t0    = (blockIdx.y * WPB + wave) * TPW;

    const float ls   = lengthscale[0];
    const float inv2 = 1.0f / (ls * ls);
    const float s1   = inv2 * LOG2E;         // dot coefficient (log2 domain)

    const int arow = rbase + (lane & 31);
    const int koff = (lane >> 5) * 8;        // canonical k-map, same for A and B

    // A fragments, loop-invariant: 4 x 16B = 16 VGPRs
    f16x8 ah[4];
    #pragma unroll
    for (int kk = 0; kk < 4; ++kk)
        ah[kk] = *reinterpret_cast<const f16x8*>(A_hi + (size_t)arow * DIM + kk * 16 + koff);

    // per-lane row constants: cn*nx for the 16 C/D rows this lane holds
    float nxc[16];
    #pragma unroll
    for (int r = 0; r < 16; ++r) {
        int row = (r & 3) + 8 * (r >> 2) + 4 * (lane >> 5);
        nxc[r] = nx2[rbase + row];
    }

    float acc[16];
    #pragma unroll
    for (int r = 0; r < 16; ++r) acc[r] = 0.0f;

    for (int t = t0; t < t0 + TPW; t += 2) {
        // Two independent tiles per iteration; fully contiguous 1KB loads.
        const _Float16* phA = B_hi + (size_t)t * 2048 + (size_t)lane * 8;
        const _Float16* phB = phA + 2048;
        f16x8 bhA[4], bhB[4];
        #pragma unroll
        for (int kk = 0; kk < 4; ++kk) {
            bhA[kk] = *reinterpret_cast<const f16x8*>(phA + kk * 512);
            bhB[kk] = *reinterpret_cast<const f16x8*>(phB + kk * 512);
        }
        const float wA = wt[t * 32 + (lane & 31)];
        const float wB = wt[(t + 1) * 32 + (lane & 31)];

        f32x16 CA = {};
        f32x16 CB = {};
        #pragma unroll
        for (int kk = 0; kk < 4; ++kk) {
            CA = __builtin_amdgcn_mfma_f32_32x32x16_f16(ah[kk], bhA[kk], CA, 0, 0, 0);
            CB = __builtin_amdgcn_mfma_f32_32x32x16_f16(ah[kk], bhB[kk], CB, 0, 0, 0);
        }

        #pragma unroll
        for (int r = 0; r < 16; ++r) {
            float argA = fmaf(CA[r], s1, nxc[r]);        // log2 domain
            float argB = fmaf(CB[r], s1, nxc[r]);
            acc[r] = fmaf(__builtin_amdgcn_exp2f(argA), wA, acc[r]);
            acc[r] = fmaf(__builtin_amdgcn_exp2f(argB), wB, acc[r]);
        }
    }

    // Sum over the 32 train cols held across lanes of the same half.
    #pragma unroll
    for (int r = 0; r < 16; ++r) {
        float v = acc[r];
        v += __shfl_xor(v, 1);  v += __shfl_xor(v, 2);  v += __shfl_xor(v, 4);
        v += __shfl_xor(v, 8);  v += __shfl_xor(v, 16);
        if ((lane & 31) == 0) {
            int row = (r & 3) + 8 * (r >> 2) + 4 * (lane >> 5);
            atomicAdd(&out[rbase + row], v);
        }
    }
}

// ---------------- fallback (round-1 kernel, known-good) ----------------
#define TCHUNK 512
#define NCHUNK (NTRAIN / TCHUNK)
__global__ __launch_bounds__(256, 4) void krr_main(
    const float* __restrict__ test_X, const float* __restrict__ train_X,
    const float* __restrict__ alphas, const float* __restrict__ lengthscale,
    float* __restrict__ out)
{
    __shared__ float nt_lds[TCHUNK];
    __shared__ float al_lds[TCHUNK];
    const int tid = threadIdx.x;
    const int i   = blockIdx.x * 256 + tid;
    const int j0  = blockIdx.y * TCHUNK;
    const float ls   = lengthscale[0];
    const float inv2 = 1.0f / (ls * ls);
    for (int jj = tid; jj < TCHUNK; jj += 256) {
        const float4* tr = reinterpret_cast<const float4*>(train_X + (size_t)(j0 + jj) * DIM);
        float s = 0.f;
        #pragma unroll
        for (int k = 0; k < DIM / 4; ++k) {
            float4 t = tr[k];
            s += t.x * t.x + t.y * t.y + t.z * t.z + t.w * t.w;
        }
        nt_lds[jj] = s * inv2;
        al_lds[jj] = alphas[j0 + jj];
    }
    __syncthreads();
    float xr[DIM]; float nxv = 0.f;
    {
        const float4* xp = reinterpret_cast<const float4*>(test_X + (size_t)i * DIM);
        #pragma unroll
        for (int k = 0; k < DIM / 4; ++k) {
            float4 v = xp[k];
            xr[4*k+0] = v.x; xr[4*k+1] = v.y; xr[4*k+2] = v.z; xr[4*k+3] = v.w;
            nxv += v.x*v.x + v.y*v.y + v.z*v.z + v.w*v.w;
        }
        nxv *= inv2;
        #pragma unroll
        for (int k = 0; k < DIM; ++k) xr[k] *= inv2;
    }
    float acc = 0.f;
    for (int jj = 0; jj < TCHUNK; ++jj) {
        const float* trow = train_X + (size_t)(j0 + jj) * DIM;
        float d0 = 0.f, d1 = 0.f, d2 = 0.f, d3 = 0.f;
        #pragma unroll
        for (int k4 = 0; k4 < DIM / 4; ++k4) {
            float4 t = reinterpret_cast<const float4*>(trow)[k4];
            d0 = fmaf(xr[4*k4+0], t.x, d0);
            d1 = fmaf(xr[4*k4+1], t.y, d1);
            d2 = fmaf(xr[4*k4+2], t.z, d2);
            d3 = fmaf(xr[4*k4+3], t.w, d3);
        }
        float dot = (d0 + d1) + (d2 + d3);
        float sq  = nxv + nt_lds[jj] - 2.0f * dot;
        sq = fmaxf(sq, 0.0f);
        acc = fmaf(__expf(-0.5f * sq), al_lds[jj], acc);
    }
    atomicAdd(&out[i], acc);
}

extern "C" void kernel_launch(void* const* d_in, const int* in_sizes, int n_in,
                              void* d_out, int out_size, void* d_ws, size_t ws_size,
                              hipStream_t stream) {
    const float* test_X      = (const float*)d_in[0];
    const float* train_X     = (const float*)d_in[1];
    const float* alphas      = (const float*)d_in[2];
    const float* lengthscale = (const float*)d_in[3];
    float* out = (float*)d_out;

    hipMemsetAsync(out, 0, NTEST * sizeof(float), stream);

    const size_t need = (size_t)(NTEST + NTRAIN) * DIM * sizeof(_Float16)
                      + (NTEST + NTRAIN) * sizeof(float);
    if (ws_size >= need) {
        _Float16* A_hi = (_Float16*)d_ws;
        _Float16* B_hi = A_hi + (size_t)NTEST * DIM;
        float*    nx2  = (float*)(B_hi + (size_t)NTRAIN * DIM);
        float*    wtp  = nx2 + NTEST;

        krr_prep<<<(NTEST + NTRAIN) / 4, 256, 0, stream>>>(
            test_X, train_X, alphas, lengthscale, A_hi, B_hi, nx2, wtp);

        dim3 grid(NTEST / 32, NCOLSPLIT / WPB);
        krr_mfma<<<grid, 64 * WPB, 0, stream>>>(A_hi, B_hi, nx2, wtp,
                                                lengthscale, out);
    } else {
        dim3 grid(NTEST / 256, NCHUNK);
        krr_main<<<grid, 256, 0, stream>>>(test_X, train_X, alphas, lengthscale, out);
    }
}